// Round 1
// baseline (305.669 us; speedup 1.0000x reference)
//
#include <hip/hip_runtime.h>
#include <stdint.h>

typedef short short8 __attribute__((ext_vector_type(8)));
typedef float f32x4 __attribute__((ext_vector_type(4)));

#define SEQ 2048
#define NBH 32   // B*H

__device__ __forceinline__ unsigned short f32_to_bf16(float f) {
  union { float f; uint32_t u; } v; v.f = f;
  return (unsigned short)((v.u + 0x7fffu + ((v.u >> 16) & 1u)) >> 16);
}

__device__ __forceinline__ void gload_lds16(const unsigned short* g, unsigned short* l) {
  __builtin_amdgcn_global_load_lds(
      (const __attribute__((address_space(1))) unsigned int*)g,
      (__attribute__((address_space(3))) unsigned int*)l, 16, 0, 0);
}

__global__ void cast_f32_bf16(const float* __restrict__ in,
                              unsigned short* __restrict__ out, int n4) {
  int i = blockIdx.x * blockDim.x + threadIdx.x;
  if (i >= n4) return;
  float4 v = ((const float4*)in)[i];
  ushort4 o;
  o.x = f32_to_bf16(v.x); o.y = f32_to_bf16(v.y);
  o.z = f32_to_bf16(v.z); o.w = f32_to_bf16(v.w);
  ((ushort4*)out)[i] = o;
}

// XOR swizzle over the 4 16B-slots of a 64B LDS row: 2-way max bank conflict
#define GSWZ(row, k) ((k) ^ ((row) & 3) ^ (((row) >> 2) & 3))

// C = A(row-major [M][1024]) * B^T (B row-major [N][1024]), 128x128 tile, BK=32,
// 256 threads = 4 waves (2x2), each wave 64x64 via 4x4 16x16x32 bf16 MFMAs.
__device__ __forceinline__ void gemm_core_1024(
    const unsigned short* __restrict__ Ag,   // pre-offset to tile-row base
    const unsigned short* __restrict__ Bg,   // pre-offset to tile-col base
    int tid, f32x4 acc[4][4])
{
  __shared__ __align__(16) unsigned short As[128 * 32];
  __shared__ __align__(16) unsigned short Bs[128 * 32];
  const int w = tid >> 6, l = tid & 63;
  const int wr = w >> 1, wc = w & 1;
  const int lc = l & 15, lg = l >> 4;

  const int c0row = tid >> 2,        c0ks = tid & 3;   // chunk t=0
  const int c1row = (256 + tid) >> 2;                  // chunk t=1 (same ks)

  for (int k0 = 0; k0 < 1024; k0 += 32) {
    int kg0 = GSWZ(c0row, c0ks);
    int kg1 = GSWZ(c1row, c0ks);
    gload_lds16(Ag + (size_t)c0row * 1024 + k0 + kg0 * 8, As + (w * 64) * 8);
    gload_lds16(Ag + (size_t)c1row * 1024 + k0 + kg1 * 8, As + (256 + w * 64) * 8);
    gload_lds16(Bg + (size_t)c0row * 1024 + k0 + kg0 * 8, Bs + (w * 64) * 8);
    gload_lds16(Bg + (size_t)c1row * 1024 + k0 + kg1 * 8, Bs + (256 + w * 64) * 8);
    __syncthreads();

    short8 a[4], b[4];
#pragma unroll
    for (int mi = 0; mi < 4; ++mi) {
      int row = wr * 64 + mi * 16 + lc;
      int ko = GSWZ(row, lg);
      a[mi] = *(const short8*)(As + row * 32 + ko * 8);
    }
#pragma unroll
    for (int ni = 0; ni < 4; ++ni) {
      int row = wc * 64 + ni * 16 + lc;
      int ko = GSWZ(row, lg);
      b[ni] = *(const short8*)(Bs + row * 32 + ko * 8);
    }
#pragma unroll
    for (int mi = 0; mi < 4; ++mi)
#pragma unroll
      for (int ni = 0; ni < 4; ++ni)
        acc[mi][ni] = __builtin_amdgcn_mfma_f32_16x16x32_bf16(a[mi], b[ni], acc[mi][ni], 0, 0, 0);
    __syncthreads();
  }
}

// QKV GEMM: A = x_bf16 [4096][1024]; B selected among Wq/Wk/Wv by tile col.
// Epilogue: +bias, cast bf16, scatter to [bh][n][64].
__global__ __launch_bounds__(256, 2)
void gemm_qkv(const unsigned short* __restrict__ XB,
              const unsigned short* __restrict__ WQB,
              const unsigned short* __restrict__ WKB,
              const unsigned short* __restrict__ WVB,
              const float* __restrict__ bq,
              const float* __restrict__ bk,
              const float* __restrict__ bv,
              unsigned short* __restrict__ Qo,
              unsigned short* __restrict__ Ko,
              unsigned short* __restrict__ Vo)
{
  const int tid = threadIdx.x;
  const int tm = blockIdx.x * 128;
  const int tn = blockIdx.y * 128;            // 0..2944
  const int wi = tn >> 10;
  const int tnl = tn & 1023;
  const unsigned short* Bw = (wi == 0 ? WQB : wi == 1 ? WKB : WVB) + (size_t)tnl * 1024;
  const float* bias = (wi == 0 ? bq : wi == 1 ? bk : bv);
  unsigned short* Out = (wi == 0 ? Qo : wi == 1 ? Ko : Vo);

  f32x4 acc[4][4];
#pragma unroll
  for (int mi = 0; mi < 4; ++mi)
#pragma unroll
    for (int ni = 0; ni < 4; ++ni)
      acc[mi][ni] = (f32x4){0.f, 0.f, 0.f, 0.f};

  gemm_core_1024(XB + (size_t)tm * 1024, Bw, tid, acc);

  const int w = tid >> 6, l = tid & 63;
  const int wr = w >> 1, wc = w & 1;
  const int lc = l & 15, lg = l >> 4;
#pragma unroll
  for (int ni = 0; ni < 4; ++ni) {
    int nl = tnl + wc * 64 + ni * 16 + lc;    // col within selected W (0..1023)
    float bb = bias[nl];
    int h = nl >> 6, d = nl & 63;
#pragma unroll
    for (int mi = 0; mi < 4; ++mi) {
#pragma unroll
      for (int r = 0; r < 4; ++r) {
        int m = tm + wr * 64 + mi * 16 + lg * 4 + r;
        int b = m >> 11, i = m & 2047;
        float v = acc[mi][ni][r] + bb;
        Out[(((size_t)(b * 16 + h) * SEQ + i) << 6) + d] = f32_to_bf16(v);
      }
    }
  }
}

// O GEMM: A = attn_flat bf16 [4096][1024]; B = Wo; out f32 + bo.
__global__ __launch_bounds__(256, 2)
void gemm_o(const unsigned short* __restrict__ AT,
            const unsigned short* __restrict__ WOB,
            const float* __restrict__ bo,
            float* __restrict__ Of)
{
  const int tid = threadIdx.x;
  const int tm = blockIdx.x * 128;
  const int tn = blockIdx.y * 128;

  f32x4 acc[4][4];
#pragma unroll
  for (int mi = 0; mi < 4; ++mi)
#pragma unroll
    for (int ni = 0; ni < 4; ++ni)
      acc[mi][ni] = (f32x4){0.f, 0.f, 0.f, 0.f};

  gemm_core_1024(AT + (size_t)tm * 1024, WOB + (size_t)tn * 1024, tid, acc);

  const int w = tid >> 6, l = tid & 63;
  const int wr = w >> 1, wc = w & 1;
  const int lc = l & 15, lg = l >> 4;
#pragma unroll
  for (int ni = 0; ni < 4; ++ni) {
    int n = tn + wc * 64 + ni * 16 + lc;
    float bb = bo[n];
#pragma unroll
    for (int mi = 0; mi < 4; ++mi) {
#pragma unroll
      for (int r = 0; r < 4; ++r) {
        int m = tm + wr * 64 + mi * 16 + lg * 4 + r;
        Of[(size_t)m * 1024 + n] = acc[mi][ni][r] + bb;
      }
    }
  }
}

// V [bh][2048][64] -> VT [bh][64][2048], 32x32 LDS tiles
__global__ void transpose_v(const unsigned short* __restrict__ V,
                            unsigned short* __restrict__ VT)
{
  __shared__ unsigned short tile[32][33];
  int bh = blockIdx.z;
  int n0 = blockIdx.x * 32, d0 = blockIdx.y * 32;
  int x = threadIdx.x;                       // 0..31
  for (int yy = threadIdx.y; yy < 32; yy += 8)
    tile[yy][x] = V[((size_t)bh * SEQ + n0 + yy) * 64 + d0 + x];
  __syncthreads();
  for (int yy = threadIdx.y; yy < 32; yy += 8)
    VT[((size_t)bh * 64 + d0 + yy) * SEQ + n0 + x] = tile[x][yy];
}

// Flash attention fwd. 4 waves/block, each wave owns 16 q-rows; block = 64 q-rows.
// grid = (SEQ/64, NBH). Q,K: [bh][n][64] bf16; VT: [bh][64][n] bf16.
// Out: [b][n][h*64+d] bf16 (flat [4096][1024]).
__global__ __launch_bounds__(256, 3)
void attn_fwd(const unsigned short* __restrict__ Qm,
              const unsigned short* __restrict__ Km,
              const unsigned short* __restrict__ VTm,
              unsigned short* __restrict__ Aout)
{
  __shared__ __align__(16) unsigned short Plds[4 * 16 * 64];  // per-wave [16][64] bf16
  const int tid = threadIdx.x, w = tid >> 6, l = tid & 63;
  const int lc = l & 15, lg = l >> 4;
  const int bh = blockIdx.y, q0 = blockIdx.x * 64;

  const unsigned short* Qb = Qm + ((size_t)bh * SEQ + q0 + w * 16) * 64;
  const unsigned short* Kb = Km + (size_t)bh * SEQ * 64;
  const unsigned short* Vb = VTm + (size_t)bh * 64 * SEQ;
  char* Pw = (char*)(Plds + w * 1024);

  // Q fragments: A[row=q(lc)][k=d], d = kq*32 + lg*8 + jj
  short8 aq0 = *(const short8*)(Qb + lc * 64 + lg * 8);
  short8 aq1 = *(const short8*)(Qb + lc * 64 + 32 + lg * 8);

  f32x4 o[4];
  float mrow[4], lrow[4];
#pragma unroll
  for (int r = 0; r < 4; ++r) { mrow[r] = -1e30f; lrow[r] = 0.f; }
#pragma unroll
  for (int dc = 0; dc < 4; ++dc) o[dc] = (f32x4){0.f, 0.f, 0.f, 0.f};

  for (int j0 = 0; j0 < SEQ; j0 += 64) {
    // S tiles: C[q=lg*4+r][j=jc*16+lc]
    f32x4 s[4];
#pragma unroll
    for (int jc = 0; jc < 4; ++jc) {
      const unsigned short* kp = Kb + (size_t)(j0 + jc * 16 + lc) * 64 + lg * 8;
      short8 b0 = *(const short8*)(kp);
      short8 b1 = *(const short8*)(kp + 32);
      f32x4 t = (f32x4){0.f, 0.f, 0.f, 0.f};
      t = __builtin_amdgcn_mfma_f32_16x16x32_bf16(aq0, b0, t, 0, 0, 0);
      t = __builtin_amdgcn_mfma_f32_16x16x32_bf16(aq1, b1, t, 0, 0, 0);
      s[jc] = t * 0.03125f;   // 1/sqrt(1024)
    }
    // per-row max over 64 j (4 regs x shfl over 16 lanes)
    float pmax[4];
#pragma unroll
    for (int r = 0; r < 4; ++r) {
      float t = fmaxf(fmaxf(s[0][r], s[1][r]), fmaxf(s[2][r], s[3][r]));
      t = fmaxf(t, __shfl_xor(t, 1));
      t = fmaxf(t, __shfl_xor(t, 2));
      t = fmaxf(t, __shfl_xor(t, 4));
      t = fmaxf(t, __shfl_xor(t, 8));
      pmax[r] = t;
    }
    float alpha[4];
#pragma unroll
    for (int r = 0; r < 4; ++r) {
      float mnew = fmaxf(mrow[r], pmax[r]);
      alpha[r] = __expf(mrow[r] - mnew);
      mrow[r] = mnew;
      lrow[r] *= alpha[r];
    }
#pragma unroll
    for (int dc = 0; dc < 4; ++dc)
#pragma unroll
      for (int r = 0; r < 4; ++r) o[dc][r] *= alpha[r];

    // P = exp(s-m): write bf16 to swizzled LDS, accumulate row sums
    float psum[4] = {0.f, 0.f, 0.f, 0.f};
#pragma unroll
    for (int jc = 0; jc < 4; ++jc) {
#pragma unroll
      for (int r = 0; r < 4; ++r) {
        float p = __expf(s[jc][r] - mrow[r]);
        psum[r] += p;
        int prow = lg * 4 + r;
        int off = (prow * 128 + (jc * 16 + lc) * 2) ^ ((prow & 7) << 4);
        *(unsigned short*)(Pw + off) = f32_to_bf16(p);
      }
    }
#pragma unroll
    for (int r = 0; r < 4; ++r) {
      float t = psum[r];
      t += __shfl_xor(t, 1);
      t += __shfl_xor(t, 2);
      t += __shfl_xor(t, 4);
      t += __shfl_xor(t, 8);
      lrow[r] += t;
    }
    // PV: o[q][d] += P[q][j] * V[j][d]; A=P from LDS, B=VT rows (16B/lane)
#pragma unroll
    for (int ks = 0; ks < 2; ++ks) {
      int off = (lc * 128 + ks * 64 + lg * 16) ^ ((lc & 7) << 4);
      short8 pa = *(const short8*)(Pw + off);
#pragma unroll
      for (int dc = 0; dc < 4; ++dc) {
        short8 bv = *(const short8*)(Vb + (size_t)(dc * 16 + lc) * SEQ + j0 + ks * 32 + lg * 8);
        o[dc] = __builtin_amdgcn_mfma_f32_16x16x32_bf16(pa, bv, o[dc], 0, 0, 0);
      }
    }
  }

  const int b = bh >> 4, h = bh & 15;
#pragma unroll
  for (int r = 0; r < 4; ++r) {
    float inv = 1.0f / lrow[r];
    int i = q0 + w * 16 + lg * 4 + r;
    size_t base = ((size_t)b * SEQ + i) * 1024 + h * 64;
#pragma unroll
    for (int dc = 0; dc < 4; ++dc)
      Aout[base + dc * 16 + lc] = f32_to_bf16(o[dc][r] * inv);
  }
}

extern "C" void kernel_launch(void* const* d_in, const int* in_sizes, int n_in,
                              void* d_out, int out_size, void* d_ws, size_t ws_size,
                              hipStream_t stream) {
  (void)in_sizes; (void)n_in; (void)out_size; (void)ws_size;
  const float* x  = (const float*)d_in[0];
  const float* Wq = (const float*)d_in[1];
  const float* bq = (const float*)d_in[2];
  const float* Wk = (const float*)d_in[3];
  const float* bk = (const float*)d_in[4];
  const float* Wv = (const float*)d_in[5];
  const float* bv = (const float*)d_in[6];
  const float* Wo = (const float*)d_in[7];
  const float* bo = (const float*)d_in[8];
  float* Of = (float*)d_out;

  // ws layout (bf16 elements); total 58,720,256 bytes
  unsigned short* ws  = (unsigned short*)d_ws;
  unsigned short* XB  = ws;               // x bf16 [4096][1024]
  unsigned short* WQB = ws + 4194304u;
  unsigned short* WKB = ws + 5242880u;
  unsigned short* WVB = ws + 6291456u;
  unsigned short* WOB = ws + 7340032u;
  unsigned short* QB  = ws + 8388608u;    // [32][2048][64]
  unsigned short* KB  = ws + 12582912u;
  unsigned short* VB  = ws + 16777216u;
  unsigned short* VTB = ws + 20971520u;   // [32][64][2048]
  unsigned short* ATB = ws + 25165824u;   // attn flat [4096][1024]

  cast_f32_bf16<<<4096, 256, 0, stream>>>(x,  XB,  1048576);
  cast_f32_bf16<<<1024, 256, 0, stream>>>(Wq, WQB, 262144);
  cast_f32_bf16<<<1024, 256, 0, stream>>>(Wk, WKB, 262144);
  cast_f32_bf16<<<1024, 256, 0, stream>>>(Wv, WVB, 262144);
  cast_f32_bf16<<<1024, 256, 0, stream>>>(Wo, WOB, 262144);

  gemm_qkv<<<dim3(32, 24), 256, 0, stream>>>(XB, WQB, WKB, WVB, bq, bk, bv, QB, KB, VB);
  transpose_v<<<dim3(64, 2, 32), dim3(32, 8), 0, stream>>>(VB, VTB);
  attn_fwd<<<dim3(32, 32), 256, 0, stream>>>(QB, KB, VTB, ATB);
  gemm_o<<<dim3(32, 8), 256, 0, stream>>>(ATB, WOB, bo, Of);
}

// Round 2
// 143.944 us; speedup vs baseline: 2.1235x; 2.1235x over previous
//
#include <hip/hip_runtime.h>
#include <stdint.h>

typedef short short8 __attribute__((ext_vector_type(8)));
typedef float f32x4 __attribute__((ext_vector_type(4)));
typedef float f32x16 __attribute__((ext_vector_type(16)));
typedef unsigned int uint2v __attribute__((ext_vector_type(2)));
typedef unsigned int uint4v __attribute__((ext_vector_type(4)));

#define SEQ 2048
#define NBH 32   // B*H

__device__ __forceinline__ unsigned short f32_to_bf16(float f) {
  union { float f; uint32_t u; } v; v.f = f;
  return (unsigned short)((v.u + 0x7fffu + ((v.u >> 16) & 1u)) >> 16);
}

__device__ __forceinline__ unsigned int cvtpk_bf16(float lo, float hi) {
  unsigned int r;
  asm("v_cvt_pk_bf16_f32 %0, %1, %2" : "=v"(r) : "v"(lo), "v"(hi));
  return r;
}

__device__ __forceinline__ void gload_lds16(const unsigned short* g, unsigned short* l) {
  __builtin_amdgcn_global_load_lds(
      (const __attribute__((address_space(1))) unsigned int*)g,
      (__attribute__((address_space(3))) unsigned int*)l, 16, 0, 0);
}

__global__ void cast_f32_bf16(const float* __restrict__ in,
                              unsigned short* __restrict__ out, int n4) {
  int i = blockIdx.x * blockDim.x + threadIdx.x;
  if (i >= n4) return;
  float4 v = ((const float4*)in)[i];
  ushort4 o;
  o.x = f32_to_bf16(v.x); o.y = f32_to_bf16(v.y);
  o.z = f32_to_bf16(v.z); o.w = f32_to_bf16(v.w);
  ((ushort4*)out)[i] = o;
}

// XOR swizzle over the 4 16B-slots of a 64B LDS row: 2-way max bank conflict
#define GSWZ(row, k) ((k) ^ ((row) & 3) ^ (((row) >> 2) & 3))

// C = A(row-major [M][1024]) * B^T (B row-major [N][1024]), 128x128 tile, BK=32,
// 256 threads = 4 waves (2x2), each wave 64x64 via 4x4 16x16x32 bf16 MFMAs.
__device__ __forceinline__ void gemm_core_1024(
    const unsigned short* __restrict__ Ag,   // pre-offset to tile-row base
    const unsigned short* __restrict__ Bg,   // pre-offset to tile-col base
    int tid, f32x4 acc[4][4])
{
  __shared__ __align__(16) unsigned short As[128 * 32];
  __shared__ __align__(16) unsigned short Bs[128 * 32];
  const int w = tid >> 6, l = tid & 63;
  const int wr = w >> 1, wc = w & 1;
  const int lc = l & 15, lg = l >> 4;

  const int c0row = tid >> 2,        c0ks = tid & 3;   // chunk t=0
  const int c1row = (256 + tid) >> 2;                  // chunk t=1 (same ks)

  for (int k0 = 0; k0 < 1024; k0 += 32) {
    int kg0 = GSWZ(c0row, c0ks);
    int kg1 = GSWZ(c1row, c0ks);
    gload_lds16(Ag + (size_t)c0row * 1024 + k0 + kg0 * 8, As + (w * 64) * 8);
    gload_lds16(Ag + (size_t)c1row * 1024 + k0 + kg1 * 8, As + (256 + w * 64) * 8);
    gload_lds16(Bg + (size_t)c0row * 1024 + k0 + kg0 * 8, Bs + (w * 64) * 8);
    gload_lds16(Bg + (size_t)c1row * 1024 + k0 + kg1 * 8, Bs + (256 + w * 64) * 8);
    __syncthreads();

    short8 a[4], b[4];
#pragma unroll
    for (int mi = 0; mi < 4; ++mi) {
      int row = wr * 64 + mi * 16 + lc;
      int ko = GSWZ(row, lg);
      a[mi] = *(const short8*)(As + row * 32 + ko * 8);
    }
#pragma unroll
    for (int ni = 0; ni < 4; ++ni) {
      int row = wc * 64 + ni * 16 + lc;
      int ko = GSWZ(row, lg);
      b[ni] = *(const short8*)(Bs + row * 32 + ko * 8);
    }
#pragma unroll
    for (int mi = 0; mi < 4; ++mi)
#pragma unroll
      for (int ni = 0; ni < 4; ++ni)
        acc[mi][ni] = __builtin_amdgcn_mfma_f32_16x16x32_bf16(a[mi], b[ni], acc[mi][ni], 0, 0, 0);
    __syncthreads();
  }
}

// QKV GEMM: A = x_bf16 [4096][1024]; B selected among Wq/Wk/Wv by tile col.
// Epilogue: +bias, cast bf16, scatter to [bh][n][64].
__global__ __launch_bounds__(256, 2)
void gemm_qkv(const unsigned short* __restrict__ XB,
              const unsigned short* __restrict__ WQB,
              const unsigned short* __restrict__ WKB,
              const unsigned short* __restrict__ WVB,
              const float* __restrict__ bq,
              const float* __restrict__ bk,
              const float* __restrict__ bv,
              unsigned short* __restrict__ Qo,
              unsigned short* __restrict__ Ko,
              unsigned short* __restrict__ Vo)
{
  const int tid = threadIdx.x;
  const int tm = blockIdx.x * 128;
  const int tn = blockIdx.y * 128;            // 0..2944
  const int wi = tn >> 10;
  const int tnl = tn & 1023;
  const unsigned short* Bw = (wi == 0 ? WQB : wi == 1 ? WKB : WVB) + (size_t)tnl * 1024;
  const float* bias = (wi == 0 ? bq : wi == 1 ? bk : bv);
  unsigned short* Out = (wi == 0 ? Qo : wi == 1 ? Ko : Vo);

  f32x4 acc[4][4];
#pragma unroll
  for (int mi = 0; mi < 4; ++mi)
#pragma unroll
    for (int ni = 0; ni < 4; ++ni)
      acc[mi][ni] = (f32x4){0.f, 0.f, 0.f, 0.f};

  gemm_core_1024(XB + (size_t)tm * 1024, Bw, tid, acc);

  const int w = tid >> 6, l = tid & 63;
  const int wr = w >> 1, wc = w & 1;
  const int lc = l & 15, lg = l >> 4;
#pragma unroll
  for (int ni = 0; ni < 4; ++ni) {
    int nl = tnl + wc * 64 + ni * 16 + lc;    // col within selected W (0..1023)
    float bb = bias[nl];
    int h = nl >> 6, d = nl & 63;
#pragma unroll
    for (int mi = 0; mi < 4; ++mi) {
#pragma unroll
      for (int r = 0; r < 4; ++r) {
        int m = tm + wr * 64 + mi * 16 + lg * 4 + r;
        int b = m >> 11, i = m & 2047;
        float v = acc[mi][ni][r] + bb;
        Out[(((size_t)(b * 16 + h) * SEQ + i) << 6) + d] = f32_to_bf16(v);
      }
    }
  }
}

// O GEMM: A = attn_flat bf16 [4096][1024]; B = Wo; out f32 + bo.
__global__ __launch_bounds__(256, 2)
void gemm_o(const unsigned short* __restrict__ AT,
            const unsigned short* __restrict__ WOB,
            const float* __restrict__ bo,
            float* __restrict__ Of)
{
  const int tid = threadIdx.x;
  const int tm = blockIdx.x * 128;
  const int tn = blockIdx.y * 128;

  f32x4 acc[4][4];
#pragma unroll
  for (int mi = 0; mi < 4; ++mi)
#pragma unroll
    for (int ni = 0; ni < 4; ++ni)
      acc[mi][ni] = (f32x4){0.f, 0.f, 0.f, 0.f};

  gemm_core_1024(AT + (size_t)tm * 1024, WOB + (size_t)tn * 1024, tid, acc);

  const int w = tid >> 6, l = tid & 63;
  const int wr = w >> 1, wc = w & 1;
  const int lc = l & 15, lg = l >> 4;
#pragma unroll
  for (int ni = 0; ni < 4; ++ni) {
    int n = tn + wc * 64 + ni * 16 + lc;
    float bb = bo[n];
#pragma unroll
    for (int mi = 0; mi < 4; ++mi) {
#pragma unroll
      for (int r = 0; r < 4; ++r) {
        int m = tm + wr * 64 + mi * 16 + lg * 4 + r;
        Of[(size_t)m * 1024 + n] = acc[mi][ni][r] + bb;
      }
    }
  }
}

// V [bh][2048][64] -> VT [bh][64][2048], 32x32 LDS tiles
__global__ void transpose_v(const unsigned short* __restrict__ V,
                            unsigned short* __restrict__ VT)
{
  __shared__ unsigned short tile[32][33];
  int bh = blockIdx.z;
  int n0 = blockIdx.x * 32, d0 = blockIdx.y * 32;
  int x = threadIdx.x;                       // 0..31
  for (int yy = threadIdx.y; yy < 32; yy += 8)
    tile[yy][x] = V[((size_t)bh * SEQ + n0 + yy) * 64 + d0 + x];
  __syncthreads();
  for (int yy = threadIdx.y; yy < 32; yy += 8)
    VT[((size_t)bh * 64 + d0 + yy) * SEQ + n0 + x] = tile[x][yy];
}

// ---------------------------------------------------------------------------
// Flash attention fwd, m214-style: 8 waves x 32 q-rows = 256 q/block.
// Swapped QK^T (mfma(K,Q)) and swapped PV (mfma(VT,P^T)) so q = lane&31 for
// m/l/o throughout. K,V in XOR-swizzled double-buffered LDS (shared by all
// waves); P converted to bf16 fragments fully in-register.
// grid = (SEQ/256, NBH), block = 512.
// Q,K: [bh][n][64] bf16; VT: [bh][64][n] bf16. Out: [b][n][h*64+d] bf16.
// ---------------------------------------------------------------------------
__global__ __launch_bounds__(512, 1)
void attn_fwd2(const unsigned short* __restrict__ Qm,
               const unsigned short* __restrict__ Km,
               const unsigned short* __restrict__ VTm,
               unsigned short* __restrict__ Aout)
{
  __shared__ __align__(16) unsigned short Ks[2][64 * 64];
  __shared__ __align__(16) unsigned short Vs[2][64 * 64];
  const int tid = threadIdx.x, w = tid >> 6, l = tid & 63;
  const int lq = l & 31, hi = l >> 5;
  const int bh = blockIdx.y, q0 = blockIdx.x * 256;

  const unsigned short* Qb = Qm + ((size_t)bh * SEQ + q0 + w * 32) * 64;
  const unsigned short* Kg = Km + (size_t)bh * SEQ * 64;
  const unsigned short* Vg = VTm + (size_t)bh * 64 * SEQ;   // [64 d][2048 j]

  // staging: wave w covers tile rows [w*8, w*8+8); lane l -> row w*8+(l>>3),
  // 16B slot l&7. LDS dest is linear; SOURCE slot pre-swizzled so that
  // LDS[r][s] = G[r][s ^ (r&7)]  (read side XORs byte with (r&7)<<4).
  const int srow = w * 8 + (l >> 3);
  const int sslot = (l & 7) ^ (l >> 3);

  // Q fragments (B-operand): col=q=lane&31, k = d = kc*16 + hi*8 + [0..7]
  short8 qf[4];
#pragma unroll
  for (int kc = 0; kc < 4; ++kc)
    qf[kc] = *(const short8*)(Qb + lq * 64 + kc * 16 + hi * 8);

  f32x16 o0, o1;
#pragma unroll
  for (int r = 0; r < 16; ++r) { o0[r] = 0.f; o1[r] = 0.f; }
  float mrow = -1e30f, lden = 0.f;

  gload_lds16(Kg + (size_t)srow * 64 + sslot * 8, &Ks[0][w * 512]);
  gload_lds16(Vg + (size_t)srow * SEQ + sslot * 8, &Vs[0][w * 512]);
  __syncthreads();   // compiler drains vmcnt before s_barrier

  for (int t = 0; t < 32; ++t) {
    const int cur = t & 1;
    if (t + 1 < 32) {
      const int j1 = (t + 1) * 64;
      gload_lds16(Kg + (size_t)(j1 + srow) * 64 + sslot * 8, &Ks[cur ^ 1][w * 512]);
      gload_lds16(Vg + (size_t)srow * SEQ + j1 + sslot * 8, &Vs[cur ^ 1][w * 512]);
    }
    const char* Kb = (const char*)Ks[cur];
    const char* Vb = (const char*)Vs[cur];

    // S^T = K*Q^T: D col=q=lane&31, row=j_local=(reg&3)+8*(reg>>2)+4*hi
    f32x16 s0, s1;
#pragma unroll
    for (int r = 0; r < 16; ++r) { s0[r] = 0.f; s1[r] = 0.f; }
#pragma unroll
    for (int kc = 0; kc < 4; ++kc) {
      const int r0 = lq;
      short8 kf = *(const short8*)(Kb + ((r0 * 128 + kc * 32 + hi * 16) ^ ((r0 & 7) << 4)));
      s0 = __builtin_amdgcn_mfma_f32_32x32x16_bf16(kf, qf[kc], s0, 0, 0, 0);
    }
#pragma unroll
    for (int kc = 0; kc < 4; ++kc) {
      const int r1 = 32 + lq;
      short8 kf = *(const short8*)(Kb + ((r1 * 128 + kc * 32 + hi * 16) ^ ((r1 & 7) << 4)));
      s1 = __builtin_amdgcn_mfma_f32_32x32x16_bf16(kf, qf[kc], s1, 0, 0, 0);
    }

    // p[js*16+reg] = S[q][ j = js*32 + (reg&3)+8*(reg>>2)+4*hi ] / 32
    float p[32];
#pragma unroll
    for (int r = 0; r < 16; ++r) { p[r] = s0[r] * 0.03125f; p[16 + r] = s1[r] * 0.03125f; }

    // row max: lane-local tree + one cross-half shfl
    float mx[16];
#pragma unroll
    for (int i = 0; i < 16; ++i) mx[i] = fmaxf(p[i], p[i + 16]);
#pragma unroll
    for (int st = 8; st > 0; st >>= 1)
#pragma unroll
      for (int i = 0; i < st; ++i) mx[i] = fmaxf(mx[i], mx[i + st]);
    float pmax = fmaxf(mx[0], __shfl_xor(mx[0], 32));

    // defer-max (T13): only rescale when the running max grew by > 8
    if (!__all(pmax - mrow <= 8.0f)) {
      float mn = fmaxf(mrow, pmax);
      float al = __expf(mrow - mn);
      mrow = mn;
      lden *= al;
#pragma unroll
      for (int r = 0; r < 16; ++r) { o0[r] *= al; o1[r] *= al; }
    }

#pragma unroll
    for (int i = 0; i < 32; ++i) p[i] = __expf(p[i] - mrow);

    float sm[16];
#pragma unroll
    for (int i = 0; i < 16; ++i) sm[i] = p[i] + p[i + 16];
#pragma unroll
    for (int st = 8; st > 0; st >>= 1)
#pragma unroll
      for (int i = 0; i < st; ++i) sm[i] += sm[i + st];
    lden += sm[0] + __shfl_xor(sm[0], 32);

    // P -> bf16 B-fragments (T12): pa[ks] holds P[q][ks*16 + hi*8 + 0..7]
    short8 pa[4];
#pragma unroll
    for (int ks = 0; ks < 4; ++ks) {
      const int pb = ks * 8;
      unsigned int a0 = cvtpk_bf16(p[pb + 0], p[pb + 1]);
      unsigned int a1 = cvtpk_bf16(p[pb + 2], p[pb + 3]);
      unsigned int b0 = cvtpk_bf16(p[pb + 4], p[pb + 5]);
      unsigned int b1 = cvtpk_bf16(p[pb + 6], p[pb + 7]);
      unsigned int a0x = __shfl_xor((int)a0, 32), b0x = __shfl_xor((int)b0, 32);
      unsigned int a1x = __shfl_xor((int)a1, 32), b1x = __shfl_xor((int)b1, 32);
      union { uint4v u; short8 s; } cvt;
      cvt.u.x = hi ? b0x : a0;   // elems j = ks*16 + hi*8 + {0,1}
      cvt.u.y = hi ? b1x : a1;   // {2,3}
      cvt.u.z = hi ? b0 : a0x;   // {4,5}
      cvt.u.w = hi ? b1 : a1x;   // {6,7}
      pa[ks] = cvt.s;
    }

    // O^T += VT * P^T: D col=q=lane&31, row=d_local
#pragma unroll
    for (int ks = 0; ks < 4; ++ks) {
      const int rv = lq;
      short8 vf = *(const short8*)(Vb + ((rv * 128 + ks * 32 + hi * 16) ^ ((rv & 7) << 4)));
      o0 = __builtin_amdgcn_mfma_f32_32x32x16_bf16(vf, pa[ks], o0, 0, 0, 0);
    }
#pragma unroll
    for (int ks = 0; ks < 4; ++ks) {
      const int rv = 32 + lq;
      short8 vf = *(const short8*)(Vb + ((rv * 128 + ks * 32 + hi * 16) ^ ((rv & 7) << 4)));
      o1 = __builtin_amdgcn_mfma_f32_32x32x16_bf16(vf, pa[ks], o1, 0, 0, 0);
    }
    __syncthreads();   // drains vmcnt (stage) + lgkm; buffers flip
  }

  // epilogue: d = dc*32 + rq*8 + hi*4 + (0..3) for o[dc] regs rq*4..rq*4+3
  const int b = bh >> 4, h = bh & 15;
  const float inv = 1.0f / lden;
  const size_t obase = ((size_t)b * SEQ + q0 + w * 32 + lq) * 1024 + h * 64;
#pragma unroll
  for (int rq = 0; rq < 4; ++rq) {
    uint2v pk0, pk1;
    pk0.x = cvtpk_bf16(o0[rq * 4 + 0] * inv, o0[rq * 4 + 1] * inv);
    pk0.y = cvtpk_bf16(o0[rq * 4 + 2] * inv, o0[rq * 4 + 3] * inv);
    pk1.x = cvtpk_bf16(o1[rq * 4 + 0] * inv, o1[rq * 4 + 1] * inv);
    pk1.y = cvtpk_bf16(o1[rq * 4 + 2] * inv, o1[rq * 4 + 3] * inv);
    *(uint2v*)(Aout + obase + rq * 8 + hi * 4) = pk0;
    *(uint2v*)(Aout + obase + 32 + rq * 8 + hi * 4) = pk1;
  }
}

extern "C" void kernel_launch(void* const* d_in, const int* in_sizes, int n_in,
                              void* d_out, int out_size, void* d_ws, size_t ws_size,
                              hipStream_t stream) {
  (void)in_sizes; (void)n_in; (void)out_size; (void)ws_size;
  const float* x  = (const float*)d_in[0];
  const float* Wq = (const float*)d_in[1];
  const float* bq = (const float*)d_in[2];
  const float* Wk = (const float*)d_in[3];
  const float* bk = (const float*)d_in[4];
  const float* Wv = (const float*)d_in[5];
  const float* bv = (const float*)d_in[6];
  const float* Wo = (const float*)d_in[7];
  const float* bo = (const float*)d_in[8];
  float* Of = (float*)d_out;

  // ws layout (bf16 elements); total 58,720,256 bytes
  unsigned short* ws  = (unsigned short*)d_ws;
  unsigned short* XB  = ws;               // x bf16 [4096][1024]
  unsigned short* WQB = ws + 4194304u;
  unsigned short* WKB = ws + 5242880u;
  unsigned short* WVB = ws + 6291456u;
  unsigned short* WOB = ws + 7340032u;
  unsigned short* QB  = ws + 8388608u;    // [32][2048][64]
  unsigned short* KB  = ws + 12582912u;
  unsigned short* VB  = ws + 16777216u;
  unsigned short* VTB = ws + 20971520u;   // [32][64][2048]
  unsigned short* ATB = ws + 25165824u;   // attn flat [4096][1024]

  cast_f32_bf16<<<4096, 256, 0, stream>>>(x,  XB,  1048576);
  cast_f32_bf16<<<1024, 256, 0, stream>>>(Wq, WQB, 262144);
  cast_f32_bf16<<<1024, 256, 0, stream>>>(Wk, WKB, 262144);
  cast_f32_bf16<<<1024, 256, 0, stream>>>(Wv, WVB, 262144);
  cast_f32_bf16<<<1024, 256, 0, stream>>>(Wo, WOB, 262144);

  gemm_qkv<<<dim3(32, 24), 256, 0, stream>>>(XB, WQB, WKB, WVB, bq, bk, bv, QB, KB, VB);
  transpose_v<<<dim3(64, 2, 32), dim3(32, 8), 0, stream>>>(VB, VTB);
  attn_fwd2<<<dim3(8, 32), 512, 0, stream>>>(QB, KB, VTB, ATB);
  gemm_o<<<dim3(32, 8), 256, 0, stream>>>(ATB, WOB, bo, Of);
}

// Round 3
// 135.704 us; speedup vs baseline: 2.2525x; 1.0607x over previous
//
#include <hip/hip_runtime.h>
#include <stdint.h>

typedef short short8 __attribute__((ext_vector_type(8)));
typedef float f32x4 __attribute__((ext_vector_type(4)));
typedef float f32x16 __attribute__((ext_vector_type(16)));
typedef unsigned int uint2v __attribute__((ext_vector_type(2)));
typedef unsigned int uint4v __attribute__((ext_vector_type(4)));

#define SEQ 2048
#define NBH 32   // B*H

__device__ __forceinline__ unsigned short f32_to_bf16(float f) {
  union { float f; uint32_t u; } v; v.f = f;
  return (unsigned short)((v.u + 0x7fffu + ((v.u >> 16) & 1u)) >> 16);
}

__device__ __forceinline__ unsigned int cvtpk_bf16(float lo, float hi) {
  unsigned int r;
  asm("v_cvt_pk_bf16_f32 %0, %1, %2" : "=v"(r) : "v"(lo), "v"(hi));
  return r;
}

__device__ __forceinline__ void gload_lds16(const unsigned short* g, unsigned short* l) {
  __builtin_amdgcn_global_load_lds(
      (const __attribute__((address_space(1))) unsigned int*)g,
      (__attribute__((address_space(3))) unsigned int*)l, 16, 0, 0);
}

__global__ void cast_f32_bf16(const float* __restrict__ in,
                              unsigned short* __restrict__ out, int n4) {
  int i = blockIdx.x * blockDim.x + threadIdx.x;
  if (i >= n4) return;
  float4 v = ((const float4*)in)[i];
  ushort4 o;
  o.x = f32_to_bf16(v.x); o.y = f32_to_bf16(v.y);
  o.z = f32_to_bf16(v.z); o.w = f32_to_bf16(v.w);
  ((ushort4*)out)[i] = o;
}

// XOR swizzle over the 4 16B-slots of a 64B LDS row: 2-way max bank conflict
#define GSWZ(row, k) ((k) ^ ((row) & 3) ^ (((row) >> 2) & 3))

// C = A(row-major [M][1024]) * B^T (B row-major [N][1024]), 128x128 tile, BK=32,
// 256 threads = 4 waves (2x2), each wave 64x64 via 4x4 16x16x32 bf16 MFMAs.
__device__ __forceinline__ void gemm_core_1024(
    const unsigned short* __restrict__ Ag,   // pre-offset to tile-row base
    const unsigned short* __restrict__ Bg,   // pre-offset to tile-col base
    int tid, f32x4 acc[4][4])
{
  __shared__ __align__(16) unsigned short As[128 * 32];
  __shared__ __align__(16) unsigned short Bs[128 * 32];
  const int w = tid >> 6, l = tid & 63;
  const int wr = w >> 1, wc = w & 1;
  const int lc = l & 15, lg = l >> 4;

  const int c0row = tid >> 2,        c0ks = tid & 3;   // chunk t=0
  const int c1row = (256 + tid) >> 2;                  // chunk t=1 (same ks)

  for (int k0 = 0; k0 < 1024; k0 += 32) {
    int kg0 = GSWZ(c0row, c0ks);
    int kg1 = GSWZ(c1row, c0ks);
    gload_lds16(Ag + (size_t)c0row * 1024 + k0 + kg0 * 8, As + (w * 64) * 8);
    gload_lds16(Ag + (size_t)c1row * 1024 + k0 + kg1 * 8, As + (256 + w * 64) * 8);
    gload_lds16(Bg + (size_t)c0row * 1024 + k0 + kg0 * 8, Bs + (w * 64) * 8);
    gload_lds16(Bg + (size_t)c1row * 1024 + k0 + kg1 * 8, Bs + (256 + w * 64) * 8);
    __syncthreads();

    short8 a[4], b[4];
#pragma unroll
    for (int mi = 0; mi < 4; ++mi) {
      int row = wr * 64 + mi * 16 + lc;
      int ko = GSWZ(row, lg);
      a[mi] = *(const short8*)(As + row * 32 + ko * 8);
    }
#pragma unroll
    for (int ni = 0; ni < 4; ++ni) {
      int row = wc * 64 + ni * 16 + lc;
      int ko = GSWZ(row, lg);
      b[ni] = *(const short8*)(Bs + row * 32 + ko * 8);
    }
#pragma unroll
    for (int mi = 0; mi < 4; ++mi)
#pragma unroll
      for (int ni = 0; ni < 4; ++ni)
        acc[mi][ni] = __builtin_amdgcn_mfma_f32_16x16x32_bf16(a[mi], b[ni], acc[mi][ni], 0, 0, 0);
    __syncthreads();
  }
}

// QKV GEMM: A = x_bf16 [4096][1024]; B selected among Wq/Wk/Wv by tile col.
// Epilogue: +bias, cast bf16, scatter to [bh][n][64].
// Q additionally scaled by log2(e)/32 so attention works in exp2 domain.
__global__ __launch_bounds__(256, 2)
void gemm_qkv(const unsigned short* __restrict__ XB,
              const unsigned short* __restrict__ WQB,
              const unsigned short* __restrict__ WKB,
              const unsigned short* __restrict__ WVB,
              const float* __restrict__ bq,
              const float* __restrict__ bk,
              const float* __restrict__ bv,
              unsigned short* __restrict__ Qo,
              unsigned short* __restrict__ Ko,
              unsigned short* __restrict__ Vo)
{
  const int tid = threadIdx.x;
  const int tm = blockIdx.x * 128;
  const int tn = blockIdx.y * 128;            // 0..2944
  const int wi = tn >> 10;
  const int tnl = tn & 1023;
  const unsigned short* Bw = (wi == 0 ? WQB : wi == 1 ? WKB : WVB) + (size_t)tnl * 1024;
  const float* bias = (wi == 0 ? bq : wi == 1 ? bk : bv);
  unsigned short* Out = (wi == 0 ? Qo : wi == 1 ? Ko : Vo);
  const float qscale = (wi == 0) ? 0.04508422002778011f : 1.0f;  // log2(e)/32

  f32x4 acc[4][4];
#pragma unroll
  for (int mi = 0; mi < 4; ++mi)
#pragma unroll
    for (int ni = 0; ni < 4; ++ni)
      acc[mi][ni] = (f32x4){0.f, 0.f, 0.f, 0.f};

  gemm_core_1024(XB + (size_t)tm * 1024, Bw, tid, acc);

  const int w = tid >> 6, l = tid & 63;
  const int wr = w >> 1, wc = w & 1;
  const int lc = l & 15, lg = l >> 4;
#pragma unroll
  for (int ni = 0; ni < 4; ++ni) {
    int nl = tnl + wc * 64 + ni * 16 + lc;    // col within selected W (0..1023)
    float bb = bias[nl];
    int h = nl >> 6, d = nl & 63;
#pragma unroll
    for (int mi = 0; mi < 4; ++mi) {
#pragma unroll
      for (int r = 0; r < 4; ++r) {
        int m = tm + wr * 64 + mi * 16 + lg * 4 + r;
        int b = m >> 11, i = m & 2047;
        float v = (acc[mi][ni][r] + bb) * qscale;
        Out[(((size_t)(b * 16 + h) * SEQ + i) << 6) + d] = f32_to_bf16(v);
      }
    }
  }
}

// O GEMM: A = attn_flat bf16 [4096][1024]; B = Wo; out f32 + bo.
__global__ __launch_bounds__(256, 2)
void gemm_o(const unsigned short* __restrict__ AT,
            const unsigned short* __restrict__ WOB,
            const float* __restrict__ bo,
            float* __restrict__ Of)
{
  const int tid = threadIdx.x;
  const int tm = blockIdx.x * 128;
  const int tn = blockIdx.y * 128;

  f32x4 acc[4][4];
#pragma unroll
  for (int mi = 0; mi < 4; ++mi)
#pragma unroll
    for (int ni = 0; ni < 4; ++ni)
      acc[mi][ni] = (f32x4){0.f, 0.f, 0.f, 0.f};

  gemm_core_1024(AT + (size_t)tm * 1024, WOB + (size_t)tn * 1024, tid, acc);

  const int w = tid >> 6, l = tid & 63;
  const int wr = w >> 1, wc = w & 1;
  const int lc = l & 15, lg = l >> 4;
#pragma unroll
  for (int ni = 0; ni < 4; ++ni) {
    int n = tn + wc * 64 + ni * 16 + lc;
    float bb = bo[n];
#pragma unroll
    for (int mi = 0; mi < 4; ++mi) {
#pragma unroll
      for (int r = 0; r < 4; ++r) {
        int m = tm + wr * 64 + mi * 16 + lg * 4 + r;
        Of[(size_t)m * 1024 + n] = acc[mi][ni][r] + bb;
      }
    }
  }
}

// V [bh][2048][64] -> VT [bh][64][2048], 32x32 LDS tiles
__global__ void transpose_v(const unsigned short* __restrict__ V,
                            unsigned short* __restrict__ VT)
{
  __shared__ unsigned short tile[32][33];
  int bh = blockIdx.z;
  int n0 = blockIdx.x * 32, d0 = blockIdx.y * 32;
  int x = threadIdx.x;                       // 0..31
  for (int yy = threadIdx.y; yy < 32; yy += 8)
    tile[yy][x] = V[((size_t)bh * SEQ + n0 + yy) * 64 + d0 + x];
  __syncthreads();
  for (int yy = threadIdx.y; yy < 32; yy += 8)
    VT[((size_t)bh * 64 + d0 + yy) * SEQ + n0 + x] = tile[x][yy];
}

// ---------------------------------------------------------------------------
// Flash attention fwd v3: 4 waves x 32 q-rows = 128 q/block, grid (32 bh, 16 q)
// -> 512 blocks = 2 independent blocks/CU (barrier overlap). K and V-transposed
// interleaved in ONE [64][128] bf16 LDS tile (256B row = 16 slots), XOR-swizzled
// over r&15 -> 2 lanes/slot = conflict-free b128 reads. Softmax in exp2 domain
// (scale*log2e pre-folded into Q). Double-buffered staging via global_load_lds
// with pre-swizzled per-lane source.
// ---------------------------------------------------------------------------
__global__ __launch_bounds__(256, 2)
void attn_fwd3(const unsigned short* __restrict__ Qm,
               const unsigned short* __restrict__ Km,
               const unsigned short* __restrict__ VTm,
               unsigned short* __restrict__ Aout)
{
  __shared__ __align__(16) unsigned short KV[2][64 * 128];
  const int tid = threadIdx.x, w = tid >> 6, l = tid & 63;
  const int lq = l & 31, hi = l >> 5;
  const int m15 = lq & 15;
  const int bh = blockIdx.x, q0 = blockIdx.y * 128;

  const unsigned short* Qb = Qm + ((size_t)bh * SEQ + q0 + w * 32) * 64;
  const unsigned short* Kg = Km + (size_t)bh * SEQ * 64;
  const unsigned short* Vg = VTm + (size_t)bh * 64 * SEQ;   // [64 d][2048 j]

  // Staging: LDS[r][s] = G[r][s ^ (r&15)], G row r = K[j0+r][0:64] | VT[r][j0:j0+64].
  // Wave w stages rows w*16..w*16+15 via 4 instrs (4 rows x 256B = 1024B each).
  const int sr = l >> 4;        // row within 4-row chunk
  const int ss = l & 15;        // 16B slot
  const unsigned short* sp[4];
  int sstep[4];
#pragma unroll
  for (int i = 0; i < 4; ++i) {
    int r = w * 16 + i * 4 + sr;
    int t = ss ^ (i * 4 + sr);                 // (r&15) == i*4+sr
    if (t < 8) { sp[i] = Kg + (size_t)r * 64 + t * 8;          sstep[i] = 64 * 64; }
    else       { sp[i] = Vg + (size_t)r * SEQ + (t - 8) * 8;   sstep[i] = 64; }
  }

  // Q fragments (B-operand): col=q=lane&31, k = d = kc*16 + hi*8 + [0..7]
  short8 qf[4];
#pragma unroll
  for (int kc = 0; kc < 4; ++kc)
    qf[kc] = *(const short8*)(Qb + lq * 64 + kc * 16 + hi * 8);

  f32x16 o0, o1;
#pragma unroll
  for (int r = 0; r < 16; ++r) { o0[r] = 0.f; o1[r] = 0.f; }
  float mrow = -1e30f, lden = 0.f;   // mrow in log2 domain

  // prologue: stage tile 0
#pragma unroll
  for (int i = 0; i < 4; ++i) {
    gload_lds16(sp[i], &KV[0][(w * 16 + i * 4) * 128]);
    sp[i] += sstep[i];
  }
  __syncthreads();

  for (int t = 0; t < 32; ++t) {
    const int cur = t & 1;
    if (t + 1 < 32) {
#pragma unroll
      for (int i = 0; i < 4; ++i) {
        gload_lds16(sp[i], &KV[cur ^ 1][(w * 16 + i * 4) * 128]);
        sp[i] += sstep[i];
      }
    }
    const char* Tb = (const char*)(&KV[cur][0]);

    // S^T = K*Q^T (already includes /sqrt(f)*log2e): col=q, row=j_local
    f32x16 s0, s1;
#pragma unroll
    for (int r = 0; r < 16; ++r) { s0[r] = 0.f; s1[r] = 0.f; }
    __builtin_amdgcn_s_setprio(1);
#pragma unroll
    for (int kc = 0; kc < 4; ++kc) {
      short8 kf = *(const short8*)(Tb + lq * 256 + (((kc * 2 + hi) ^ m15) << 4));
      s0 = __builtin_amdgcn_mfma_f32_32x32x16_bf16(kf, qf[kc], s0, 0, 0, 0);
    }
#pragma unroll
    for (int kc = 0; kc < 4; ++kc) {
      short8 kf = *(const short8*)(Tb + (32 + lq) * 256 + (((kc * 2 + hi) ^ m15) << 4));
      s1 = __builtin_amdgcn_mfma_f32_32x32x16_bf16(kf, qf[kc], s1, 0, 0, 0);
    }
    __builtin_amdgcn_s_setprio(0);

    float p[32];
#pragma unroll
    for (int r = 0; r < 16; ++r) { p[r] = s0[r]; p[16 + r] = s1[r]; }

    // row max: lane-local tree + one cross-half shfl
    float mx[16];
#pragma unroll
    for (int i = 0; i < 16; ++i) mx[i] = fmaxf(p[i], p[i + 16]);
#pragma unroll
    for (int st = 8; st > 0; st >>= 1)
#pragma unroll
      for (int i = 0; i < st; ++i) mx[i] = fmaxf(mx[i], mx[i + st]);
    float pmax = fmaxf(mx[0], __shfl_xor(mx[0], 32));

    // defer-max (T13): threshold 11.5 in log2 domain (= e^8 bound)
    if (!__all(pmax - mrow <= 11.5f)) {
      float mn = fmaxf(mrow, pmax);
      float al = __builtin_amdgcn_exp2f(mrow - mn);
      mrow = mn;
      lden *= al;
#pragma unroll
      for (int r = 0; r < 16; ++r) { o0[r] *= al; o1[r] *= al; }
    }

#pragma unroll
    for (int i = 0; i < 32; ++i) p[i] = __builtin_amdgcn_exp2f(p[i] - mrow);

    float sm[16];
#pragma unroll
    for (int i = 0; i < 16; ++i) sm[i] = p[i] + p[i + 16];
#pragma unroll
    for (int st = 8; st > 0; st >>= 1)
#pragma unroll
      for (int i = 0; i < st; ++i) sm[i] += sm[i + st];
    lden += sm[0] + __shfl_xor(sm[0], 32);

    // P -> bf16 B-fragments (T12): pa[ks] holds P[q][ks*16 + hi*8 + 0..7]
    short8 pa[4];
#pragma unroll
    for (int ks = 0; ks < 4; ++ks) {
      const int pb = ks * 8;
      unsigned int a0 = cvtpk_bf16(p[pb + 0], p[pb + 1]);
      unsigned int a1 = cvtpk_bf16(p[pb + 2], p[pb + 3]);
      unsigned int b0 = cvtpk_bf16(p[pb + 4], p[pb + 5]);
      unsigned int b1 = cvtpk_bf16(p[pb + 6], p[pb + 7]);
      unsigned int a0x = __shfl_xor((int)a0, 32), b0x = __shfl_xor((int)b0, 32);
      unsigned int a1x = __shfl_xor((int)a1, 32), b1x = __shfl_xor((int)b1, 32);
      union { uint4v u; short8 s; } cvt;
      cvt.u.x = hi ? b0x : a0;   // elems j = ks*16 + hi*8 + {0,1}
      cvt.u.y = hi ? b1x : a1;   // {2,3}
      cvt.u.z = hi ? b0 : a0x;   // {4,5}
      cvt.u.w = hi ? b1 : a1x;   // {6,7}
      pa[ks] = cvt.s;
    }

    // O^T += VT * P^T: col=q, row=d_local; V slots are 8..15 of each row
    __builtin_amdgcn_s_setprio(1);
#pragma unroll
    for (int ks = 0; ks < 4; ++ks) {
      short8 vf = *(const short8*)(Tb + lq * 256 + (((8 + ks * 2 + hi) ^ m15) << 4));
      o0 = __builtin_amdgcn_mfma_f32_32x32x16_bf16(vf, pa[ks], o0, 0, 0, 0);
    }
#pragma unroll
    for (int ks = 0; ks < 4; ++ks) {
      short8 vf = *(const short8*)(Tb + (32 + lq) * 256 + (((8 + ks * 2 + hi) ^ m15) << 4));
      o1 = __builtin_amdgcn_mfma_f32_32x32x16_bf16(vf, pa[ks], o1, 0, 0, 0);
    }
    __builtin_amdgcn_s_setprio(0);
    __syncthreads();   // drains vmcnt (stage) + lgkm; buffers flip
  }

  // epilogue: d = dc*32 + rq*8 + hi*4 + (0..3)
  const int b = bh >> 4, h = bh & 15;
  const float inv = 1.0f / lden;
  const size_t obase = ((size_t)b * SEQ + q0 + w * 32 + lq) * 1024 + h * 64;
#pragma unroll
  for (int rq = 0; rq < 4; ++rq) {
    uint2v pk0, pk1;
    pk0.x = cvtpk_bf16(o0[rq * 4 + 0] * inv, o0[rq * 4 + 1] * inv);
    pk0.y = cvtpk_bf16(o0[rq * 4 + 2] * inv, o0[rq * 4 + 3] * inv);
    pk1.x = cvtpk_bf16(o1[rq * 4 + 0] * inv, o1[rq * 4 + 1] * inv);
    pk1.y = cvtpk_bf16(o1[rq * 4 + 2] * inv, o1[rq * 4 + 3] * inv);
    *(uint2v*)(Aout + obase + rq * 8 + hi * 4) = pk0;
    *(uint2v*)(Aout + obase + 32 + rq * 8 + hi * 4) = pk1;
  }
}

extern "C" void kernel_launch(void* const* d_in, const int* in_sizes, int n_in,
                              void* d_out, int out_size, void* d_ws, size_t ws_size,
                              hipStream_t stream) {
  (void)in_sizes; (void)n_in; (void)out_size; (void)ws_size;
  const float* x  = (const float*)d_in[0];
  const float* Wq = (const float*)d_in[1];
  const float* bq = (const float*)d_in[2];
  const float* Wk = (const float*)d_in[3];
  const float* bk = (const float*)d_in[4];
  const float* Wv = (const float*)d_in[5];
  const float* bv = (const float*)d_in[6];
  const float* Wo = (const float*)d_in[7];
  const float* bo = (const float*)d_in[8];
  float* Of = (float*)d_out;

  // ws layout (bf16 elements); total 58,720,256 bytes
  unsigned short* ws  = (unsigned short*)d_ws;
  unsigned short* XB  = ws;               // x bf16 [4096][1024]
  unsigned short* WQB = ws + 4194304u;
  unsigned short* WKB = ws + 5242880u;
  unsigned short* WVB = ws + 6291456u;
  unsigned short* WOB = ws + 7340032u;
  unsigned short* QB  = ws + 8388608u;    // [32][2048][64]
  unsigned short* KB  = ws + 12582912u;
  unsigned short* VB  = ws + 16777216u;
  unsigned short* VTB = ws + 20971520u;   // [32][64][2048]
  unsigned short* ATB = ws + 25165824u;   // attn flat [4096][1024]

  cast_f32_bf16<<<4096, 256, 0, stream>>>(x,  XB,  1048576);
  cast_f32_bf16<<<1024, 256, 0, stream>>>(Wq, WQB, 262144);
  cast_f32_bf16<<<1024, 256, 0, stream>>>(Wk, WKB, 262144);
  cast_f32_bf16<<<1024, 256, 0, stream>>>(Wv, WVB, 262144);
  cast_f32_bf16<<<1024, 256, 0, stream>>>(Wo, WOB, 262144);

  gemm_qkv<<<dim3(32, 24), 256, 0, stream>>>(XB, WQB, WKB, WVB, bq, bk, bv, QB, KB, VB);
  transpose_v<<<dim3(64, 2, 32), dim3(32, 8), 0, stream>>>(VB, VTB);
  attn_fwd3<<<dim3(32, 16), 256, 0, stream>>>(QB, KB, VTB, ATB);
  gemm_o<<<dim3(32, 8), 256, 0, stream>>>(ATB, WOB, bo, Of);
}